// Round 1
// baseline (492.034 us; speedup 1.0000x reference)
//
#include <hip/hip_runtime.h>
#include <hip/hip_bf16.h>

#define NB 4
#define NC 64
#define NN 6400
#define BN_EPS 1e-5f

typedef __attribute__((ext_vector_type(4))) float f32x4;
typedef __attribute__((ext_vector_type(8))) __bf16 bf16x8;

static __device__ __forceinline__ f32x4 mfma_bf16(bf16x8 a, bf16x8 b, f32x4 c) {
    return __builtin_amdgcn_mfma_f32_16x16x32_bf16(a, b, c, 0, 0, 0);
}

// ---------------------------------------------------------------------------
// Kernel 1: theta/phi/g 1x1 convs. Outputs:
//   Qh/Ql  [B][N][C] bf16 hi/lo split of theta
//   Kh/Kl  [B][N][C] bf16 hi/lo split of phi^T (K[n][c] = phi[c][n])
//   Vt     [B][C][N] bf16 of g (Vt[c][n] = g[c][n])
// ---------------------------------------------------------------------------
__global__ __launch_bounds__(256) void k_qkv(
    const float* __restrict__ x,
    const float* __restrict__ w_th, const float* __restrict__ b_th,
    const float* __restrict__ w_ph, const float* __restrict__ b_ph,
    const float* __restrict__ w_g,  const float* __restrict__ b_g,
    __hip_bfloat16* __restrict__ Qh, __hip_bfloat16* __restrict__ Ql,
    __hip_bfloat16* __restrict__ Kh, __hip_bfloat16* __restrict__ Kl,
    __hip_bfloat16* __restrict__ Vt)
{
    __shared__ float xs[NC][68];   // [c][p], padded
    __shared__ float ws[NC][65];   // [c][o], transposed weights, padded

    const int bid = blockIdx.x;
    const int b   = bid / (NN / 64);
    const int n0  = (bid % (NN / 64)) * 64;
    const int t   = threadIdx.x;
    const int o   = t & 63;
    const int pr  = (t >> 6) * 16;

    // stage x tile: x[b][c][n0 .. n0+64)
    {
        const int r  = t >> 2;
        const int cc = (t & 3) * 16;
        const float4* src = reinterpret_cast<const float4*>(x + (size_t)(b * NC + r) * NN + n0 + cc);
        float4* dst = reinterpret_cast<float4*>(&xs[r][cc]);
        dst[0] = src[0]; dst[1] = src[1]; dst[2] = src[2]; dst[3] = src[3];
    }

    const float* wptr[3] = { w_th, w_ph, w_g };
    const float* bptr[3] = { b_th, b_ph, b_g };

    #pragma unroll
    for (int cv = 0; cv < 3; ++cv) {
        __syncthreads();   // protect ws (and first time, complete xs staging)
        {
            const int oo = t & 63;
            const int cb = (t >> 6) * 16;
            const float4* src = reinterpret_cast<const float4*>(wptr[cv] + oo * NC + cb);
            float4 a0 = src[0], a1 = src[1], a2 = src[2], a3 = src[3];
            ws[cb +  0][oo] = a0.x; ws[cb +  1][oo] = a0.y; ws[cb +  2][oo] = a0.z; ws[cb +  3][oo] = a0.w;
            ws[cb +  4][oo] = a1.x; ws[cb +  5][oo] = a1.y; ws[cb +  6][oo] = a1.z; ws[cb +  7][oo] = a1.w;
            ws[cb +  8][oo] = a2.x; ws[cb +  9][oo] = a2.y; ws[cb + 10][oo] = a2.z; ws[cb + 11][oo] = a2.w;
            ws[cb + 12][oo] = a3.x; ws[cb + 13][oo] = a3.y; ws[cb + 14][oo] = a3.z; ws[cb + 15][oo] = a3.w;
        }
        __syncthreads();

        float acc[16];
        const float bb = bptr[cv][o];
        #pragma unroll
        for (int i = 0; i < 16; ++i) acc[i] = bb;

        #pragma unroll 8
        for (int c = 0; c < NC; ++c) {
            const float wv = ws[c][o];
            const float4* xr = reinterpret_cast<const float4*>(&xs[c][pr]);
            #pragma unroll
            for (int q = 0; q < 4; ++q) {
                const float4 xv = xr[q];
                acc[4*q + 0] = fmaf(wv, xv.x, acc[4*q + 0]);
                acc[4*q + 1] = fmaf(wv, xv.y, acc[4*q + 1]);
                acc[4*q + 2] = fmaf(wv, xv.z, acc[4*q + 2]);
                acc[4*q + 3] = fmaf(wv, xv.w, acc[4*q + 3]);
            }
        }

        if (cv < 2) {
            __hip_bfloat16* Hh = (cv == 0) ? Qh : Kh;
            __hip_bfloat16* Hl = (cv == 0) ? Ql : Kl;
            #pragma unroll
            for (int pp = 0; pp < 16; ++pp) {
                const float a = acc[pp];
                const __hip_bfloat16 h  = __float2bfloat16(a);
                const __hip_bfloat16 lo = __float2bfloat16(a - __bfloat162float(h));
                const size_t off = (size_t)(b * NN + n0 + pr + pp) * NC + o;
                Hh[off] = h;
                Hl[off] = lo;
            }
        } else {
            alignas(16) unsigned short gv[16];
            #pragma unroll
            for (int pp = 0; pp < 16; ++pp) {
                const __hip_bfloat16 h = __float2bfloat16(acc[pp]);
                gv[pp] = __builtin_bit_cast(unsigned short, h);
            }
            uint4* dst = reinterpret_cast<uint4*>(Vt + (size_t)(b * NC + o) * NN + n0 + pr);
            const uint4* srcv = reinterpret_cast<const uint4*>(gv);
            dst[0] = srcv[0];
            dst[1] = srcv[1];
        }
    }
}

// ---------------------------------------------------------------------------
// Kernel 2: flash attention. 4 waves/block, each wave owns 16 q-rows.
// KV tiles of 32 keys staged in LDS. QK^T with hi/lo bf16 split (fp32-accurate
// logits), online softmax, PV in plain bf16. Writes y [B][N][C] fp32.
// ---------------------------------------------------------------------------
__global__ __launch_bounds__(256) void k_attn(
    const __hip_bfloat16* __restrict__ Qh, const __hip_bfloat16* __restrict__ Ql,
    const __hip_bfloat16* __restrict__ Kh, const __hip_bfloat16* __restrict__ Kl,
    const __hip_bfloat16* __restrict__ Vt, float* __restrict__ y)
{
    __shared__ __hip_bfloat16 Ksh[32][72];     // [key][c] hi, row 144 B
    __shared__ __hip_bfloat16 Ksl[32][72];     // [key][c] lo
    __shared__ __hip_bfloat16 Vs[64][40];      // [c][key], row 80 B
    __shared__ __hip_bfloat16 Ps[4][16][40];   // per-wave P tile [q][key]

    const int bid = blockIdx.x;
    const int b   = bid / (NN / 64);
    const int q0  = (bid % (NN / 64)) * 64;
    const int t   = threadIdx.x;
    const int w   = t >> 6;
    const int l   = t & 63;
    const int l16 = l & 15;
    const int lg  = l >> 4;

    // Q fragments (A operand): row = l16, k = lg*8 + j
    const size_t qrow = (size_t)(b * NN + q0 + w * 16 + l16) * NC;
    const bf16x8 qh0 = *reinterpret_cast<const bf16x8*>(Qh + qrow + lg * 8);
    const bf16x8 qh1 = *reinterpret_cast<const bf16x8*>(Qh + qrow + 32 + lg * 8);
    const bf16x8 ql0 = *reinterpret_cast<const bf16x8*>(Ql + qrow + lg * 8);
    const bf16x8 ql1 = *reinterpret_cast<const bf16x8*>(Ql + qrow + 32 + lg * 8);

    f32x4 accO[4];
    float mr[4], lr[4];
    const f32x4 zero4 = {0.f, 0.f, 0.f, 0.f};
    #pragma unroll
    for (int i = 0; i < 4; ++i) { accO[i] = zero4; mr[i] = -3.0e38f; lr[i] = 0.f; }

    const __hip_bfloat16* KhB = Kh + (size_t)b * NN * NC;
    const __hip_bfloat16* KlB = Kl + (size_t)b * NN * NC;
    const __hip_bfloat16* VtB = Vt + (size_t)b * NC * NN;

    for (int kb = 0; kb < NN / 32; ++kb) {
        const int key0 = kb * 32;
        __syncthreads();   // previous tile fully consumed
        {   // stage K hi/lo: 32 rows x 128 B each
            const int r  = t >> 3;
            const int ch = t & 7;
            const uint4* sh = reinterpret_cast<const uint4*>(KhB + (size_t)(key0 + r) * NC) + ch;
            const uint4* sl = reinterpret_cast<const uint4*>(KlB + (size_t)(key0 + r) * NC) + ch;
            *reinterpret_cast<uint4*>(&Ksh[r][ch * 8]) = *sh;
            *reinterpret_cast<uint4*>(&Ksl[r][ch * 8]) = *sl;
        }
        {   // stage V^T slice: 64 rows x 64 B each
            const int r  = t >> 2;
            const int ch = t & 3;
            const uint4* sv = reinterpret_cast<const uint4*>(VtB + (size_t)r * NN + key0) + ch;
            *reinterpret_cast<uint4*>(&Vs[r][ch * 8]) = *sv;
        }
        __syncthreads();

        // ---- QK^T: S[q][key], two 16-key subtiles, hi/lo split ----
        f32x4 s0 = zero4, s1 = zero4;
        {
            const bf16x8 kh00 = *reinterpret_cast<const bf16x8*>(&Ksh[l16][lg * 8]);
            const bf16x8 kh01 = *reinterpret_cast<const bf16x8*>(&Ksh[l16][32 + lg * 8]);
            const bf16x8 kl00 = *reinterpret_cast<const bf16x8*>(&Ksl[l16][lg * 8]);
            const bf16x8 kl01 = *reinterpret_cast<const bf16x8*>(&Ksl[l16][32 + lg * 8]);
            s0 = mfma_bf16(qh0, kh00, s0);
            s0 = mfma_bf16(ql0, kh00, s0);
            s0 = mfma_bf16(qh0, kl00, s0);
            s0 = mfma_bf16(qh1, kh01, s0);
            s0 = mfma_bf16(ql1, kh01, s0);
            s0 = mfma_bf16(qh1, kl01, s0);
            const bf16x8 kh10 = *reinterpret_cast<const bf16x8*>(&Ksh[16 + l16][lg * 8]);
            const bf16x8 kh11 = *reinterpret_cast<const bf16x8*>(&Ksh[16 + l16][32 + lg * 8]);
            const bf16x8 kl10 = *reinterpret_cast<const bf16x8*>(&Ksl[16 + l16][lg * 8]);
            const bf16x8 kl11 = *reinterpret_cast<const bf16x8*>(&Ksl[16 + l16][32 + lg * 8]);
            s1 = mfma_bf16(qh0, kh10, s1);
            s1 = mfma_bf16(ql0, kh10, s1);
            s1 = mfma_bf16(qh0, kl10, s1);
            s1 = mfma_bf16(qh1, kh11, s1);
            s1 = mfma_bf16(ql1, kh11, s1);
            s1 = mfma_bf16(qh1, kl11, s1);
        }

        // ---- online softmax (rows = lg*4 + r, cols spread over 16 lanes) ----
        float pm[4];
        #pragma unroll
        for (int r = 0; r < 4; ++r) pm[r] = fmaxf(s0[r], s1[r]);
        #pragma unroll
        for (int sh = 1; sh < 16; sh <<= 1) {
            #pragma unroll
            for (int r = 0; r < 4; ++r) pm[r] = fmaxf(pm[r], __shfl_xor(pm[r], sh, 64));
        }
        float al[4];
        #pragma unroll
        for (int r = 0; r < 4; ++r) {
            const float nm = fmaxf(mr[r], pm[r]);
            al[r] = __expf(mr[r] - nm);
            mr[r] = nm;
        }
        float p0[4], p1[4], rs[4];
        #pragma unroll
        for (int r = 0; r < 4; ++r) {
            p0[r] = __expf(s0[r] - mr[r]);
            p1[r] = __expf(s1[r] - mr[r]);
            rs[r] = p0[r] + p1[r];
        }
        #pragma unroll
        for (int sh = 1; sh < 16; sh <<= 1) {
            #pragma unroll
            for (int r = 0; r < 4; ++r) rs[r] += __shfl_xor(rs[r], sh, 64);
        }
        #pragma unroll
        for (int r = 0; r < 4; ++r) {
            lr[r] = lr[r] * al[r] + rs[r];
            accO[0][r] *= al[r];
            accO[1][r] *= al[r];
            accO[2][r] *= al[r];
            accO[3][r] *= al[r];
        }
        // store P tile (D-layout -> LDS row-major [q][key])
        #pragma unroll
        for (int r = 0; r < 4; ++r) {
            Ps[w][lg * 4 + r][l16]      = __float2bfloat16(p0[r]);
            Ps[w][lg * 4 + r][16 + l16] = __float2bfloat16(p1[r]);
        }
        __syncthreads();   // order P write -> P read (also aligns waves)

        // ---- PV: A = P[q][key] (K=32), B = V[key][ch] via Vt rows ----
        {
            const bf16x8 pa = *reinterpret_cast<const bf16x8*>(&Ps[w][l16][lg * 8]);
            #pragma unroll
            for (int c4 = 0; c4 < 4; ++c4) {
                const bf16x8 vb = *reinterpret_cast<const bf16x8*>(&Vs[c4 * 16 + l16][lg * 8]);
                accO[c4] = mfma_bf16(pa, vb, accO[c4]);
            }
        }
    }

    float inv[4];
    #pragma unroll
    for (int r = 0; r < 4; ++r) inv[r] = 1.0f / lr[r];
    #pragma unroll
    for (int c4 = 0; c4 < 4; ++c4) {
        #pragma unroll
        for (int r = 0; r < 4; ++r) {
            const int q = q0 + w * 16 + lg * 4 + r;
            y[(size_t)(b * NN + q) * NC + c4 * 16 + l16] = accO[c4][r] * inv[r];
        }
    }
}

// ---------------------------------------------------------------------------
// Kernel 3: W conv (y [B][N][C] -> Wy [B][C][N]) + BN partial sums
// ---------------------------------------------------------------------------
__global__ __launch_bounds__(256) void k_wconv(
    const float* __restrict__ y, const float* __restrict__ w_W,
    const float* __restrict__ b_W, float* __restrict__ Wy,
    float* __restrict__ stats)
{
    __shared__ float ys[NC][68];   // [c][p] (transposed during staging)
    __shared__ float ws[NC][65];   // [c][o]

    const int bid = blockIdx.x;
    const int b   = bid / (NN / 64);
    const int n0  = (bid % (NN / 64)) * 64;
    const int t   = threadIdx.x;
    const int o   = t & 63;
    const int pr  = (t >> 6) * 16;

    {   // stage y tile transposed: y[b][n0+p][c] -> ys[c][p]
        const int p  = t >> 2;
        const int cb = (t & 3) * 16;
        const float4* src = reinterpret_cast<const float4*>(y + (size_t)(b * NN + n0 + p) * NC + cb);
        float4 a0 = src[0], a1 = src[1], a2 = src[2], a3 = src[3];
        ys[cb +  0][p] = a0.x; ys[cb +  1][p] = a0.y; ys[cb +  2][p] = a0.z; ys[cb +  3][p] = a0.w;
        ys[cb +  4][p] = a1.x; ys[cb +  5][p] = a1.y; ys[cb +  6][p] = a1.z; ys[cb +  7][p] = a1.w;
        ys[cb +  8][p] = a2.x; ys[cb +  9][p] = a2.y; ys[cb + 10][p] = a2.z; ys[cb + 11][p] = a2.w;
        ys[cb + 12][p] = a3.x; ys[cb + 13][p] = a3.y; ys[cb + 14][p] = a3.z; ys[cb + 15][p] = a3.w;
    }
    {   // stage weights transposed
        const int oo = t & 63;
        const int cb = (t >> 6) * 16;
        const float4* src = reinterpret_cast<const float4*>(w_W + oo * NC + cb);
        float4 a0 = src[0], a1 = src[1], a2 = src[2], a3 = src[3];
        ws[cb +  0][oo] = a0.x; ws[cb +  1][oo] = a0.y; ws[cb +  2][oo] = a0.z; ws[cb +  3][oo] = a0.w;
        ws[cb +  4][oo] = a1.x; ws[cb +  5][oo] = a1.y; ws[cb +  6][oo] = a1.z; ws[cb +  7][oo] = a1.w;
        ws[cb +  8][oo] = a2.x; ws[cb +  9][oo] = a2.y; ws[cb + 10][oo] = a2.z; ws[cb + 11][oo] = a2.w;
        ws[cb + 12][oo] = a3.x; ws[cb + 13][oo] = a3.y; ws[cb + 14][oo] = a3.z; ws[cb + 15][oo] = a3.w;
    }
    __syncthreads();

    float acc[16];
    const float bb = b_W[o];
    #pragma unroll
    for (int i = 0; i < 16; ++i) acc[i] = bb;

    #pragma unroll 8
    for (int c = 0; c < NC; ++c) {
        const float wv = ws[c][o];
        const float4* xr = reinterpret_cast<const float4*>(&ys[c][pr]);
        #pragma unroll
        for (int q = 0; q < 4; ++q) {
            const float4 xv = xr[q];
            acc[4*q + 0] = fmaf(wv, xv.x, acc[4*q + 0]);
            acc[4*q + 1] = fmaf(wv, xv.y, acc[4*q + 1]);
            acc[4*q + 2] = fmaf(wv, xv.z, acc[4*q + 2]);
            acc[4*q + 3] = fmaf(wv, xv.w, acc[4*q + 3]);
        }
    }

    float s1 = 0.f, s2 = 0.f;
    #pragma unroll
    for (int i = 0; i < 16; ++i) { s1 += acc[i]; s2 += acc[i] * acc[i]; }

    float4* dst = reinterpret_cast<float4*>(Wy + (size_t)(b * NC + o) * NN + n0 + pr);
    const float4* av = reinterpret_cast<const float4*>(acc);
    dst[0] = av[0]; dst[1] = av[1]; dst[2] = av[2]; dst[3] = av[3];

    atomicAdd(&stats[o], s1);
    atomicAdd(&stats[NC + o], s2);
}

__global__ void k_zero(float* __restrict__ stats) {
    stats[threadIdx.x] = 0.f;
}

// ---------------------------------------------------------------------------
// Kernel 4: BN (training stats) + gamma/beta + residual
// ---------------------------------------------------------------------------
__global__ __launch_bounds__(256) void k_bn(
    const float* __restrict__ Wy, const float* __restrict__ x,
    const float* __restrict__ stats, const float* __restrict__ gamma,
    const float* __restrict__ beta, float* __restrict__ out)
{
    const int i = blockIdx.x * 256 + threadIdx.x;     // float4 index
    const int c = (i / (NN / 4)) % NC;
    const float n_inv = 1.0f / (float)(NB * NN);
    const float mean = stats[c] * n_inv;
    const float var  = stats[NC + c] * n_inv - mean * mean;
    const float sc   = rsqrtf(var + BN_EPS) * gamma[c];
    const float sh   = beta[c] - mean * rsqrtf(var + BN_EPS) * gamma[c];

    const float4 wv = reinterpret_cast<const float4*>(Wy)[i];
    const float4 xv = reinterpret_cast<const float4*>(x)[i];
    float4 ov;
    ov.x = wv.x * sc + sh + xv.x;
    ov.y = wv.y * sc + sh + xv.y;
    ov.z = wv.z * sc + sh + xv.z;
    ov.w = wv.w * sc + sh + xv.w;
    reinterpret_cast<float4*>(out)[i] = ov;
}

// ---------------------------------------------------------------------------
extern "C" void kernel_launch(void* const* d_in, const int* in_sizes, int n_in,
                              void* d_out, int out_size, void* d_ws, size_t ws_size,
                              hipStream_t stream)
{
    const float* x     = (const float*)d_in[0];
    const float* w_th  = (const float*)d_in[1];
    const float* b_th  = (const float*)d_in[2];
    const float* w_ph  = (const float*)d_in[3];
    const float* b_ph  = (const float*)d_in[4];
    const float* w_g   = (const float*)d_in[5];
    const float* b_g   = (const float*)d_in[6];
    const float* w_W   = (const float*)d_in[7];
    const float* b_W   = (const float*)d_in[8];
    const float* gamma = (const float*)d_in[9];
    const float* beta  = (const float*)d_in[10];
    float* out = (float*)d_out;

    char* p = (char*)d_ws;
    const size_t nbh = (size_t)NB * NN * NC * sizeof(__hip_bfloat16);
    __hip_bfloat16* Qh = (__hip_bfloat16*)p; p += nbh;
    __hip_bfloat16* Ql = (__hip_bfloat16*)p; p += nbh;
    __hip_bfloat16* Kh = (__hip_bfloat16*)p; p += nbh;
    __hip_bfloat16* Kl = (__hip_bfloat16*)p; p += nbh;
    __hip_bfloat16* Vt = (__hip_bfloat16*)p; p += nbh;
    float* yb    = (float*)p; p += (size_t)NB * NN * NC * sizeof(float);
    float* Wy    = (float*)p; p += (size_t)NB * NN * NC * sizeof(float);
    float* stats = (float*)p;

    hipLaunchKernelGGL(k_qkv, dim3(NB * NN / 64), dim3(256), 0, stream,
                       x, w_th, b_th, w_ph, b_ph, w_g, b_g, Qh, Ql, Kh, Kl, Vt);
    hipLaunchKernelGGL(k_attn, dim3(NB * NN / 64), dim3(256), 0, stream,
                       Qh, Ql, Kh, Kl, Vt, yb);
    hipLaunchKernelGGL(k_zero, dim3(1), dim3(2 * NC), 0, stream, stats);
    hipLaunchKernelGGL(k_wconv, dim3(NB * NN / 64), dim3(256), 0, stream,
                       yb, w_W, b_W, Wy, stats);
    hipLaunchKernelGGL(k_bn, dim3((NB * NC * NN / 4) / 256), dim3(256), 0, stream,
                       Wy, x, stats, gamma, beta, out);
}